// Round 2
// baseline (308.708 us; speedup 1.0000x reference)
//
#include <hip/hip_runtime.h>

typedef float f32x4 __attribute__((ext_vector_type(4)));

// Problem constants (from reference setup_inputs)
constexpr int kB = 16, kQ = 900, kC = 91, kT = 4800;
constexpr int kBQ = kB * kQ;          // 14400
constexpr int kTI = 16;               // queries (i rows) per block
constexpr int kJT = 4;                // targets (j) per thread -> dwordx4 stores
constexpr int kBT = 256;              // threads per block
constexpr int kJB = kBT * kJT;        // 1024 j per block
constexpr int kCDS = 20;              // LDS cdT row stride (floats): 16 data + 4 pad
                                      // 80B stride: 16B-aligned b128, start banks
                                      // spread over 8 positions (20*c mod 32)

// ---------------------------------------------------------------------------
// Kernel A: cd[BQ,C] = W_CLASS*(pos-neg) + 2
//   The +2 is the giou constant: -2*giou = -2*iou + 2*(1 - uni/enc)
//   -> fold the "+2" here so kernel B needs one fewer op per element.
// ---------------------------------------------------------------------------
__global__ __launch_bounds__(256)
void class_cost_kernel(const float* __restrict__ logits,
                       float* __restrict__ cd, int n) {
    int idx = blockIdx.x * 256 + threadIdx.x;
    if (idx >= n) return;
    float x = logits[idx];
    float p = 1.0f / (1.0f + expf(-x));          // sigmoid, fp32 like ref
    float omp = 1.0f - p;
    float pos = 0.25f * omp * omp * (-logf(p + 1e-8f));
    float neg = 0.75f * p * p * (-logf(omp + 1e-8f));
    cd[idx] = 2.0f * (pos - neg) + 2.0f;         // W_CLASS + giou const folded
}

// ---------------------------------------------------------------------------
// Kernel B: cost matrix out[BQ, T]
//   grid = (ceil(T/1024), BQ/16), block = 256.
//   Theory this round: latency-bound, not issue-bound. So:
//   - __launch_bounds__(256,4): cap 128 VGPR -> 4 waves/SIMD.
//   - full static unroll: cd-row LDS base addrs computed ONCE, all 16
//     ds_read_b128 use offset: immediates; scheduler pipelines them.
//   - pred_boxes read at block-uniform addr -> s_load_dwordx4 (no lds_pb).
//   - plain (cached) stores: the harness fill sustains 6.25 TB/s with the
//     same pattern; NT store reverted (A/B vs round 1).
// ---------------------------------------------------------------------------
__global__ __launch_bounds__(256, 4)
void cost_kernel(const float* __restrict__ pred_boxes,   // [BQ,4] cxcywh
                 const int*   __restrict__ tgt_ids,      // [T] 1-based
                 const float* __restrict__ tgt_boxes,    // [T,4] cxcywh
                 const float* __restrict__ cd,           // [BQ,C] weighted (+2)
                 float*       __restrict__ out) {        // [BQ,T]
    __shared__ float lds_cdT[kC * kCDS];  // 91 x 20 x 4B = 7280 B, [c][i]

    const int tid = threadIdx.x;
    const int i0  = blockIdx.y * kTI;
    const int j0  = blockIdx.x * kJB + tid * kJT;

    // Stage cd rows i0..i0+15 transposed: global read coalesced (row-major),
    // scattered LDS write, 6 iterations total -> negligible.
    for (int k = tid; k < kTI * kC; k += kBT) {
        int i = k / kC, c = k - i * kC;
        lds_cdT[c * kCDS + i] = cd[(i0 + i) * kC + c];
    }
    __syncthreads();

    // T%4==0 -> all-or-nothing per thread; single barrier is above.
    if (j0 + kJT > kT) return;

    // Per-thread target data: load + convert ONCE (reused across 16 i's)
    int4 ids = *reinterpret_cast<const int4*>(&tgt_ids[j0]);
    // LDS row base pointers (byte addr in VGPR, computed once; all reads
    // below become ds_read_b128 vaddr offset:ig*16)
    const float* rowp[kJT] = {
        &lds_cdT[(ids.x - 1) * kCDS], &lds_cdT[(ids.y - 1) * kCDS],
        &lds_cdT[(ids.z - 1) * kCDS], &lds_cdT[(ids.w - 1) * kCDS] };

    float tcx[kJT], tcy[kJT], tw[kJT], th[kJT];
    float tx0[kJT], ty0[kJT], tx1[kJT], ty1[kJT], ta[kJT];
    #pragma unroll
    for (int q = 0; q < kJT; ++q) {
        float4 tb = reinterpret_cast<const float4*>(tgt_boxes)[j0 + q];
        tcx[q] = tb.x; tcy[q] = tb.y; tw[q] = tb.z; th[q] = tb.w;
        tx0[q] = tb.x - 0.5f * tb.z;  ty0[q] = tb.y - 0.5f * tb.w;
        tx1[q] = tb.x + 0.5f * tb.z;  ty1[q] = tb.y + 0.5f * tb.w;
        ta[q]  = tb.z * tb.w;
    }

    const size_t row0 = (size_t)i0 * kT + j0;

    #pragma unroll
    for (int ig = 0; ig < kTI / 4; ++ig) {
        // One b128 per target: cd[i0+ig*4 .. +3][class[q]]  (imm offset)
        f32x4 cdv[kJT];
        #pragma unroll
        for (int q = 0; q < kJT; ++q)
            cdv[q] = *reinterpret_cast<const f32x4*>(rowp[q] + ig * 4);

        #pragma unroll
        for (int i2 = 0; i2 < 4; ++i2) {
            const int ii = ig * 4 + i2;
            // Block-uniform address -> s_load_dwordx4 broadcast, no LDS.
            const float4 pb = reinterpret_cast<const float4*>(pred_boxes)[i0 + ii];
            const float pcx = pb.x, pcy = pb.y, pw = pb.z, ph = pb.w;
            const float px0 = pcx - 0.5f * pw, py0 = pcy - 0.5f * ph;
            const float px1 = pcx + 0.5f * pw, py1 = pcy + 0.5f * ph;
            const float pa  = pw * ph;

            f32x4 res;
            #pragma unroll
            for (int q = 0; q < kJT; ++q) {
                const float cdvq = cdv[q][i2];  // static index -> register

                float dx = pcx - tcx[q], dy = pcy - tcy[q];
                float dw = pw  - tw[q],  dh = ph  - th[q];
                float l1 = (fabsf(dx) + fabsf(dy)) + (fabsf(dw) + fabsf(dh));

                float lx = fmaxf(px0, tx0[q]), ly = fmaxf(py0, ty0[q]);
                float rx = fminf(px1, tx1[q]), ry = fminf(py1, ty1[q]);
                float iwr = rx - lx, ihr = ry - ly;
                float inter = fmaxf(iwr, 0.f) * fmaxf(ihr, 0.f);

                // max(a,b)=a+b-min(a,b): enclosing box without extra min/max;
                // ew = pw+tw-iwr >= max(pw,tw) >= 0 exactly -> no clamp.
                float ew  = (pw + tw[q]) - iwr;
                float eh  = (ph + th[q]) - ihr;
                float enc = ew * eh;
                float uni = (pa + ta[q]) - inter;

                float rcpu = __builtin_amdgcn_rcpf(fmaxf(uni, 1e-6f));
                float rcpe = __builtin_amdgcn_rcpf(fmaxf(enc, 1e-6f));

                // c = (cd+2) + 5*l1 - 2*iou - 2*uni/enc
                //   (== cd + 5*l1 - 2*iou + 2*(enc-uni)/enc when enc>=eps)
                float c = fmaf(5.0f, l1, cdvq);
                c = fmaf(-2.0f, inter * rcpu, c);
                c = fmaf(-2.0f, uni * rcpe, c);
                res[q] = c;
            }

            *reinterpret_cast<f32x4*>(&out[row0 + (size_t)ii * kT]) = res;
        }
    }
}

extern "C" void kernel_launch(void* const* d_in, const int* in_sizes, int n_in,
                              void* d_out, int out_size, void* d_ws, size_t ws_size,
                              hipStream_t stream) {
    const float* logits  = (const float*)d_in[0];   // [16,900,91]
    const float* pboxes  = (const float*)d_in[1];   // [16,900,4]
    const int*   tids    = (const int*)d_in[2];     // [4800]
    const float* tboxes  = (const float*)d_in[3];   // [4800,4]
    float* out = (float*)d_out;                     // [16,900,4800]
    float* cd  = (float*)d_ws;                      // [14400,91] = 5.24 MB

    const int n_cd = kBQ * kC;
    class_cost_kernel<<<(n_cd + 255) / 256, 256, 0, stream>>>(logits, cd, n_cd);

    dim3 grid((kT + kJB - 1) / kJB, kBQ / kTI);     // (5, 900)
    cost_kernel<<<grid, 256, 0, stream>>>(pboxes, tids, tboxes, cd, out);
}

// Round 3
// 308.090 us; speedup vs baseline: 1.0020x; 1.0020x over previous
//
#include <hip/hip_runtime.h>

typedef float f32x4 __attribute__((ext_vector_type(4)));

// Problem constants (from reference setup_inputs)
constexpr int kB = 16, kQ = 900, kC = 91, kT = 4800;
constexpr int kBQ = kB * kQ;          // 14400
constexpr int kTI = 8;                // queries (i rows) per block
constexpr int kJT = 4;                // targets (j) per thread -> dwordx4 stores
constexpr int kBT = 256;              // threads per block
constexpr int kJB = kBT * kJT;        // 1024 j per j-tile
constexpr int kNT = (kT + kJB - 1) / kJB;  // 5 j-tiles (last one partial: 704)
constexpr int kCDS = 12;              // LDS cdT row stride (floats): 8 data + 4 pad
                                      // 48B stride: 16B-aligned b128; start banks
                                      // (12*c mod 32) hit all 8 4-bank groups

// ---------------------------------------------------------------------------
// Single fused kernel: out[BQ,T], grid = BQ/8 = 1800 blocks, 256 threads.
//   Round-3 theory: the cost kernel is already at its store-bound floor
//   (3 schedule variants tied). Remaining controllable fat = the separate
//   class-cost kernel launch + the cd[BQ,C] HBM round-trip. Fuse: each block
//   computes its own 8x91 cd tile straight into transposed LDS from logits
//   (coalesced; zero redundancy since each block owns all of T for its rows).
//   Body is bit-identical to round 2.
// ---------------------------------------------------------------------------
__global__ __launch_bounds__(256, 4)
void fused_cost_kernel(const float* __restrict__ logits,      // [BQ,C]
                       const float* __restrict__ pred_boxes,  // [BQ,4] cxcywh
                       const int*   __restrict__ tgt_ids,     // [T] 1-based
                       const float* __restrict__ tgt_boxes,   // [T,4] cxcywh
                       float*       __restrict__ out) {       // [BQ,T]
    __shared__ float lds_cdT[kC * kCDS];  // 91 x 12 x 4B = 4368 B, [c][i]

    const int tid = threadIdx.x;
    const int i0  = blockIdx.x * kTI;

    // cd tile: cd = W_CLASS*(pos-neg) + 2  (giou "+2" folded, see below).
    // logits[i0*kC + k] is coalesced (k = i*91 + c walks rows contiguously);
    // 728 elements over 256 threads = 3 iterations.
    for (int k = tid; k < kTI * kC; k += kBT) {
        float x = logits[i0 * kC + k];
        float p = 1.0f / (1.0f + expf(-x));          // sigmoid, fp32 like ref
        float omp = 1.0f - p;
        float pos = 0.25f * omp * omp * (-logf(p + 1e-8f));
        float neg = 0.75f * p * p * (-logf(omp + 1e-8f));
        int i = k / kC, c = k - i * kC;
        lds_cdT[c * kCDS + i] = 2.0f * (pos - neg) + 2.0f;
    }
    __syncthreads();

    // j-tile loop: this block covers ALL of T for its 8 rows.
    for (int jt = 0; jt < kNT; ++jt) {
        const int j0 = jt * kJB + tid * kJT;
        if (j0 >= kT) continue;   // partial last tile (T%kJB=704); no barrier below

        // Per-thread target data for this tile (reused across 8 i's)
        int4 ids = *reinterpret_cast<const int4*>(&tgt_ids[j0]);
        // 32-bit LDS row offsets, computed once; reads below use imm offsets.
        const float* rowp[kJT] = {
            &lds_cdT[(ids.x - 1) * kCDS], &lds_cdT[(ids.y - 1) * kCDS],
            &lds_cdT[(ids.z - 1) * kCDS], &lds_cdT[(ids.w - 1) * kCDS] };

        float tcx[kJT], tcy[kJT], tw[kJT], th[kJT];
        float tx0[kJT], ty0[kJT], tx1[kJT], ty1[kJT], ta[kJT];
        #pragma unroll
        for (int q = 0; q < kJT; ++q) {
            float4 tb = reinterpret_cast<const float4*>(tgt_boxes)[j0 + q];
            tcx[q] = tb.x; tcy[q] = tb.y; tw[q] = tb.z; th[q] = tb.w;
            tx0[q] = tb.x - 0.5f * tb.z;  ty0[q] = tb.y - 0.5f * tb.w;
            tx1[q] = tb.x + 0.5f * tb.z;  ty1[q] = tb.y + 0.5f * tb.w;
            ta[q]  = tb.z * tb.w;
        }

        #pragma unroll
        for (int ig = 0; ig < kTI / 4; ++ig) {
            // One ds_read_b128 per target: cd[i0+ig*4 .. +3][class[q]]
            f32x4 cdv[kJT];
            #pragma unroll
            for (int q = 0; q < kJT; ++q)
                cdv[q] = *reinterpret_cast<const f32x4*>(rowp[q] + ig * 4);

            #pragma unroll
            for (int i2 = 0; i2 < 4; ++i2) {
                const int ii = ig * 4 + i2;
                // Block-uniform -> s_load_dwordx4 broadcast (L1-resident).
                const float4 pb =
                    reinterpret_cast<const float4*>(pred_boxes)[i0 + ii];
                const float pcx = pb.x, pcy = pb.y, pw = pb.z, ph = pb.w;
                const float px0 = pcx - 0.5f * pw, py0 = pcy - 0.5f * ph;
                const float px1 = pcx + 0.5f * pw, py1 = pcy + 0.5f * ph;
                const float pa  = pw * ph;

                f32x4 res;
                #pragma unroll
                for (int q = 0; q < kJT; ++q) {
                    const float cdvq = cdv[q][i2];  // static index -> register

                    float dx = pcx - tcx[q], dy = pcy - tcy[q];
                    float dw = pw  - tw[q],  dh = ph  - th[q];
                    float l1 = (fabsf(dx) + fabsf(dy)) + (fabsf(dw) + fabsf(dh));

                    float lx = fmaxf(px0, tx0[q]), ly = fmaxf(py0, ty0[q]);
                    float rx = fminf(px1, tx1[q]), ry = fminf(py1, ty1[q]);
                    float iwr = rx - lx, ihr = ry - ly;
                    float inter = fmaxf(iwr, 0.f) * fmaxf(ihr, 0.f);

                    // max(a,b)=a+b-min(a,b): enclosing box w/o extra min/max;
                    // ew = pw+tw-iwr >= max(pw,tw) >= 0 exactly -> no clamp.
                    float ew  = (pw + tw[q]) - iwr;
                    float eh  = (ph + th[q]) - ihr;
                    float enc = ew * eh;
                    float uni = (pa + ta[q]) - inter;

                    float rcpu = __builtin_amdgcn_rcpf(fmaxf(uni, 1e-6f));
                    float rcpe = __builtin_amdgcn_rcpf(fmaxf(enc, 1e-6f));

                    // c = (cd+2) + 5*l1 - 2*iou - 2*uni/enc
                    //   == cd + 5*l1 - 2*(iou - (enc-uni)/enc) for enc>=eps
                    float c = fmaf(5.0f, l1, cdvq);
                    c = fmaf(-2.0f, inter * rcpu, c);
                    c = fmaf(-2.0f, uni * rcpe, c);
                    res[q] = c;
                }

                // 32-bit element index (BQ*T = 69.12M < 2^31) -> cheap addr.
                unsigned idx = (unsigned)(i0 + ii) * (unsigned)kT + (unsigned)j0;
                *reinterpret_cast<f32x4*>(&out[idx]) = res;
            }
        }
    }
}

extern "C" void kernel_launch(void* const* d_in, const int* in_sizes, int n_in,
                              void* d_out, int out_size, void* d_ws, size_t ws_size,
                              hipStream_t stream) {
    const float* logits  = (const float*)d_in[0];   // [16,900,91]
    const float* pboxes  = (const float*)d_in[1];   // [16,900,4]
    const int*   tids    = (const int*)d_in[2];     // [4800]
    const float* tboxes  = (const float*)d_in[3];   // [4800,4]
    float* out = (float*)d_out;                     // [16,900,4800]
    (void)d_ws; (void)ws_size;                      // workspace no longer needed

    fused_cost_kernel<<<kBQ / kTI, kBT, 0, stream>>>(logits, pboxes, tids,
                                                     tboxes, out);
}